// Round 5
// baseline (1023.149 us; speedup 1.0000x reference)
//
#include <hip/hip_runtime.h>
#include <hip/hip_bf16.h>

typedef __hip_bfloat16 bf16;
typedef short short8 __attribute__((ext_vector_type(8)));
typedef float floatx4 __attribute__((ext_vector_type(4)));

#define S 256
#define H 512
#define P 32896            // S*(S+1)/2
#define NROWS 65792        // B*P
#define NEGF -1e30f
#define EPSF 1e-12f

// ---------------- ws layout (bytes) ----------------
#define OFF_SEQ    0u          // f32 [B*S*H]
#define OFF_CSUM   1048576u    // f32 [B*S*H]
#define OFF_LN1    2129920u    // f32 [B*S*H]
#define OFF_G1     3178496u    // f32 [B*S*H]
#define OFF_B1     4227072u    // f32 [B*S*H]
#define OFF_WCAT   5275648u    // bf16 [1024*512]
#define OFF_II     6324224u    // u16 [P]
#define OFF_JJ     6390016u    // u16 [P]
#define OFF_MU2    6455808u    // f32 [NROWS]
#define OFF_INV2   6718976u    // f32 [NROWS]
#define OFF_INNER  6982144u    // bf16 [NROWS*H]
// tot (f32 [64*H] = 128 KB) overlays the head of OFF_INNER (consumed by fusedB
// before inner_kernel overwrites the region).

// async 16B global->LDS (lane-linear dest: base + lane*16)
__device__ __forceinline__ void gld_lds16(const void* g, void* l) {
    __builtin_amdgcn_global_load_lds(
        (const __attribute__((address_space(1))) void*)g,
        (__attribute__((address_space(3))) void*)l, 16, 0, 0);
}

// ---------------- fused A: seq+scan1+LN1 (blocks 0..63) | prep (64..1152) ----------------
// prep: wcatT row (n) interleave at 32-col granularity: GEMM block t uses
// wcatT rows [t*256, t*256+256); quarter wn (64 rows) = 32 G2 cols
// (h = t*128 + wn*32 + 0..31) then the MATCHING 32 B2 cols -> register-only
// LN2 epilogue (each wave owns matching G2/B2 fragments).
__global__ __launch_bounds__(512) void fusedA_kernel(
    const float* __restrict__ x, const float* __restrict__ mask,
    float* __restrict__ seq, float* __restrict__ tot, float* __restrict__ ln1,
    const float* __restrict__ Wg2, const float* __restrict__ Wb2,
    bf16* __restrict__ wcatT,
    unsigned short* __restrict__ ii, unsigned short* __restrict__ jj) {
    __shared__ float part[8][8][2];
    __shared__ float rstat[8][2];
    if (blockIdx.x < 64) {
        // ---- seq + partial sums + fused LN1 (8 s-rows per block) ----
        int b = blockIdx.x >> 5, sc = blockIdx.x & 31, h = threadIdx.x;
        int wave = h >> 6, lane = h & 63;
        int s0 = sc * 8;
        float v[8];
        float run = 0.0f;
#pragma unroll
        for (int t = 0; t < 8; ++t) {
            int s = s0 + t;
            v[t] = x[(size_t)(b * S + s) * H + h] + (1.0f - mask[b * S + s]) * (-1000.0f);
            seq[(size_t)(b * S + s) * H + h] = v[t];
            run += v[t];
        }
        tot[(size_t)blockIdx.x * H + h] = run;
#pragma unroll
        for (int t = 0; t < 8; ++t) {
            float s = v[t], q = v[t] * v[t];
            for (int o = 1; o < 64; o <<= 1) { s += __shfl_xor(s, o); q += __shfl_xor(q, o); }
            if (lane == 0) { part[wave][t][0] = s; part[wave][t][1] = q; }
        }
        __syncthreads();
        if (h < 16) {
            int row = h >> 1, st = h & 1;
            float a = 0.0f;
#pragma unroll
            for (int w = 0; w < 8; ++w) a += part[w][row][st];
            rstat[row][st] = a;
        }
        __syncthreads();
#pragma unroll
        for (int t = 0; t < 8; ++t) {
            float m = rstat[t][0] * (1.0f / 512.0f);
            float var = rstat[t][1] * (1.0f / 512.0f) - m * m;
            var = var < 0.0f ? 0.0f : var;
            float inv = rsqrtf(var + EPSF);
            ln1[(size_t)(b * S + s0 + t) * H + h] = (v[t] - m) * inv;
        }
    } else {
        int n = blockIdx.x - 64;
        if (n < 1024) {
            int k = threadIdx.x;
            int tt = n >> 8, c = n & 255;
            int wn = c >> 6, u = c & 63;
            int h = tt * 128 + wn * 32 + (u & 31);
            float v = (u < 32) ? Wg2[(size_t)k * H + h] : Wb2[(size_t)k * H + h];
            wcatT[(size_t)n * H + k] = __float2bfloat16(v);
        } else {
            int p = (n - 1024) * 512 + threadIdx.x;
            if (p >= P) return;
            float disc = 513.0f * 513.0f - 8.0f * (float)p;
            int i = (int)((513.0f - sqrtf(disc)) * 0.5f);
            i = i < 0 ? 0 : (i > S - 1 ? S - 1 : i);
            while (i > 0 && (i * S - i * (i - 1) / 2) > p) --i;
            while (i < S - 1 && ((i + 1) * S - (i + 1) * i / 2) <= p) ++i;
            int off = i * S - i * (i - 1) / 2;
            ii[p] = (unsigned short)i;
            jj[p] = (unsigned short)(i + (p - off));
        }
    }
}

// ---------------- fused B: scan2 (blocks 0..63) | g1b1 (64..319) ----------------
__global__ __launch_bounds__(512) void fusedB_kernel(
    const float* __restrict__ seq, const float* __restrict__ tot,
    float* __restrict__ csum,
    const float* __restrict__ Wg1, const float* __restrict__ Wb1,
    const float* __restrict__ g1, const float* __restrict__ b1,
    float* __restrict__ G1, float* __restrict__ B1) {
    __shared__ float rowbuf[4][H];
    if (blockIdx.x < 64) {
        int b = blockIdx.x >> 5, sc = blockIdx.x & 31, h = threadIdx.x;
        float run = 0.0f;
        for (int c = 0; c < sc; ++c) run += tot[(size_t)(b * 32 + c) * H + h];
        int s0 = sc * 8;
#pragma unroll
        for (int t = 0; t < 8; ++t) {
            run += seq[(size_t)(b * S + s0 + t) * H + h];
            csum[(size_t)(b * S + s0 + t) * H + h] = run;
        }
    } else {
        // ---- G1/B1 = bias + seq @ W1 (4 rows per block; float4 LDS reads) ----
        int idx = blockIdx.x - 64;          // 0..255
        int grp = idx >> 1, mat = idx & 1;
        int h = threadIdx.x;
        int r0 = grp * 4;
        for (int r = 0; r < 4; ++r) rowbuf[r][h] = seq[(size_t)(r0 + r) * H + h];
        __syncthreads();
        const float* W = mat ? Wb1 : Wg1;
        float acc[4] = {0, 0, 0, 0};
#pragma unroll 2
        for (int k4 = 0; k4 < 128; ++k4) {
            float4 r0v = ((const float4*)rowbuf[0])[k4];
            float4 r1v = ((const float4*)rowbuf[1])[k4];
            float4 r2v = ((const float4*)rowbuf[2])[k4];
            float4 r3v = ((const float4*)rowbuf[3])[k4];
            float w0 = W[(size_t)(k4 * 4 + 0) * H + h];
            float w1 = W[(size_t)(k4 * 4 + 1) * H + h];
            float w2 = W[(size_t)(k4 * 4 + 2) * H + h];
            float w3 = W[(size_t)(k4 * 4 + 3) * H + h];
            acc[0] += r0v.x * w0 + r0v.y * w1 + r0v.z * w2 + r0v.w * w3;
            acc[1] += r1v.x * w0 + r1v.y * w1 + r1v.z * w2 + r1v.w * w3;
            acc[2] += r2v.x * w0 + r2v.y * w1 + r2v.z * w2 + r2v.w * w3;
            acc[3] += r3v.x * w0 + r3v.y * w1 + r3v.z * w2 + r3v.w * w3;
        }
        float bias = (mat ? b1 : g1)[h];
        float* dst = mat ? B1 : G1;
        for (int r = 0; r < 4; ++r) dst[(size_t)(r0 + r) * H + h] = acc[r] + bias;
    }
}

// ---------------- inner[p][h] = lam*mean + (1-lam)*max (bf16x2, balanced) ----------------
// j-loop unrolled x4: 8 independent L2 loads in flight per step.
__global__ __launch_bounds__(256) void inner_kernel(
    const float* __restrict__ seq, const float* __restrict__ csum,
    const float* __restrict__ lamtha, bf16* __restrict__ inner) {
    int id = blockIdx.x;
    int t = id & 255, b = id >> 8;
    int i = b ? (255 - t) : t;
    int h2 = threadIdx.x;                 // float2 index, 0..255
    float2 lam = ((const float2*)lamtha)[h2];
    float2 oml = {1.0f - lam.x, 1.0f - lam.y};
    const float2* seqb = (const float2*)(seq + (size_t)b * S * H);
    const float2* csb = (const float2*)(csum + (size_t)b * S * H);
    float2 s_i = seqb[i * 256 + h2];
    float2 c_i = csb[i * 256 + h2];
    float2 mrun = {NEGF, NEGF};
    size_t base = (size_t)b * P + (size_t)(i * S - i * (i - 1) / 2);
    __hip_bfloat162* dst = (__hip_bfloat162*)inner;
    int j = i;
#define INNER_STEP(vv, cc, jx)                                             \
    {                                                                      \
        mrun.x = fmaxf(mrun.x, vv.x);                                      \
        mrun.y = fmaxf(mrun.y, vv.y);                                      \
        float rl = 1.0f / (float)((jx) - i + 1);                           \
        float mx = (cc.x - c_i.x + s_i.x) * rl;                            \
        float my = (cc.y - c_i.y + s_i.y) * rl;                            \
        __hip_bfloat162 o;                                                 \
        o.x = __float2bfloat16(lam.x * mx + oml.x * mrun.x);               \
        o.y = __float2bfloat16(lam.y * my + oml.y * mrun.y);               \
        dst[(base + (size_t)((jx) - i)) * 256 + h2] = o;                   \
    }
    for (; j + 4 <= S; j += 4) {
        float2 v0 = seqb[(j + 0) * 256 + h2], c0 = csb[(j + 0) * 256 + h2];
        float2 v1 = seqb[(j + 1) * 256 + h2], c1 = csb[(j + 1) * 256 + h2];
        float2 v2 = seqb[(j + 2) * 256 + h2], c2 = csb[(j + 2) * 256 + h2];
        float2 v3 = seqb[(j + 3) * 256 + h2], c3 = csb[(j + 3) * 256 + h2];
        INNER_STEP(v0, c0, j + 0)
        INNER_STEP(v1, c1, j + 1)
        INNER_STEP(v2, c2, j + 2)
        INNER_STEP(v3, c3, j + 3)
    }
    for (; j < S; ++j) {
        float2 v = seqb[j * 256 + h2];
        float2 c = csb[j * 256 + h2];
        INNER_STEP(v, c, j)
    }
#undef INNER_STEP
}

// ---------------- LN2 row stats: wave per pair-row (float4 loads) ----------------
__global__ void stats_kernel(const float* __restrict__ ln1, const float* __restrict__ G1,
                             const float* __restrict__ B1,
                             const unsigned short* __restrict__ ii,
                             const unsigned short* __restrict__ jj,
                             float* __restrict__ mu2, float* __restrict__ inv2) {
    int r = blockIdx.x * 4 + (threadIdx.x >> 6);
    int lane = threadIdx.x & 63;
    int b = (r >= P) ? 1 : 0;
    int p = r - b * P;
    int i = ii[p], j = jj[p];
    const float4* lp = (const float4*)(ln1 + (size_t)(b * S + j) * H);
    const float4* gp = (const float4*)(G1 + (size_t)(b * S + i) * H);
    const float4* bp = (const float4*)(B1 + (size_t)(b * S + i) * H);
    float sum = 0.0f, ss = 0.0f;
#pragma unroll
    for (int t = 0; t < 2; ++t) {
        int idx = t * 64 + lane;
        float4 a = lp[idx], g = gp[idx], bb = bp[idx];
        float v0 = a.x * g.x + bb.x, v1 = a.y * g.y + bb.y;
        float v2 = a.z * g.z + bb.z, v3 = a.w * g.w + bb.w;
        sum += (v0 + v1) + (v2 + v3);
        ss += (v0 * v0 + v1 * v1) + (v2 * v2 + v3 * v3);
    }
    for (int o = 1; o < 64; o <<= 1) { sum += __shfl_xor(sum, o); ss += __shfl_xor(ss, o); }
    if (lane == 0) {
        float m = sum * (1.0f / 512.0f);
        float var = ss * (1.0f / 512.0f) - m * m;
        var = var < 0.0f ? 0.0f : var;
        mu2[r] = m;
        inv2[r] = rsqrtf(var + EPSF);
    }
}

// ---------------- fused GEMM (inner @ [Wg2|Wb2]) + LN2 epilogue ----------------
// 256x256 block tile, 8 waves (2M x 4N, wave tile 128x64), BK=32,
// LDS double-buffered 64 KB -> 2 blocks/CU (16 waves/CU).
// Rationale: R3's 128^2/4-wave schema measured LDS-BW-bound (~184 B/cy at
// MfmaUtil 29%). Block-level LDS bytes/MAC = sum(Mw+Nw)/(Mb*Nb): this shape
// gives 0.0469 vs 0.0625 -> MfmaUtil cap ~50%.
// BK=32 -> 64B logical rows; stored PAIRED: physical row (128 B) = two
// consecutive logical rows, chunks XOR-swizzled by (prow&7). All fragment
// row-bases are ==0 mod 16 so the swizzle term is lane-constant; per-16-lane
// phase each bank-group serves exactly 2 lanes (free).
// Pipeline identical to proven: stage kt+2 after lgkmcnt(0)+barrier between
// the two MFMA half-clusters; steady vmcnt(4); never 0 mid-loop.
// Grid 1028 = 257 row-panels x 4 htiles (65792 = 257*256: NO row tail);
// decode keeps a panel's 4 htiles on ONE XCD (panel HBM-fetched once).
__global__ __launch_bounds__(512, 4) void gemm_kernel(
    const bf16* __restrict__ inner, const bf16* __restrict__ wcatT,
    const float* __restrict__ g2, const float* __restrict__ b2,
    const float* __restrict__ ln1, const float* __restrict__ G1, const float* __restrict__ B1,
    const unsigned short* __restrict__ ii, const unsigned short* __restrict__ jj,
    const float* __restrict__ mu2, const float* __restrict__ inv2,
    float* __restrict__ out) {
    extern __shared__ __align__(16) char smem[];   // 65536: 2 bufs x (A 16K | B 16K)

    const int tid = threadIdx.x;
    const int wave = tid >> 6, lane = tid & 63;
    const int q = lane >> 4, l15 = lane & 15;
    const int wm = wave & 1, wn = wave >> 1;       // wm 0..1, wn 0..3

    // XCD-aware decode: super-tiles of 8 row-panels x 4 htiles
    const int id = blockIdx.x;
    int rb, t;
    if (id < 1024) { rb = (id >> 5) * 8 + (id & 7); t = (id >> 3) & 3; }
    else           { rb = 256; t = id - 1024; }
    const int R0 = rb * 256;

    // staging source decode: LDS chunk ci (16B units) -> (logical row, col-quad)
    // phys: prow = ci>>3, pc = ci&7; logical l = pc ^ (prow&7);
    // row = 2*prow + (l>>2), cq = l&3  (inverse of the read-side swizzle)
    int row0, cq0, row1, cq1;
    {
        int ci = tid;
        int pr = ci >> 3, pc = ci & 7, l = pc ^ (pr & 7);
        row0 = (pr << 1) | (l >> 2); cq0 = l & 3;
    }
    {
        int ci = 512 + tid;
        int pr = ci >> 3, pc = ci & 7, l = pc ^ (pr & 7);
        row1 = (pr << 1) | (l >> 2); cq1 = l & 3;
    }
    const bf16* const Ag0 = inner + (size_t)(R0 + row0) * H + cq0 * 8;
    const bf16* const Ag1 = inner + (size_t)(R0 + row1) * H + cq1 * 8;
    const bf16* const Bg0 = wcatT + (size_t)(t * 256 + row0) * H + cq0 * 8;
    const bf16* const Bg1 = wcatT + (size_t)(t * 256 + row1) * H + cq1 * 8;

    // read-side lane constants
    const int prl = l15 >> 1;                               // 0..7
    const int apc = (((((l15 & 1) << 2) | q)) ^ prl) << 4;  // swizzled 16B chunk
    const int C = prl * 128 + apc;

    floatx4 acc[8][4];
#pragma unroll
    for (int a = 0; a < 8; ++a)
#pragma unroll
        for (int c = 0; c < 4; ++c) acc[a][c] = (floatx4){0.f, 0.f, 0.f, 0.f};

    auto STAGE = [&](int kt, int bufbase) {
        gld_lds16(Ag0 + kt * 32, smem + bufbase + wave * 1024);
        gld_lds16(Ag1 + kt * 32, smem + bufbase + 8192 + wave * 1024);
        gld_lds16(Bg0 + kt * 32, smem + bufbase + 16384 + wave * 1024);
        gld_lds16(Bg1 + kt * 32, smem + bufbase + 24576 + wave * 1024);
    };

    // prologue: fill both buffers; wait only the first (4 loads stay in flight)
    STAGE(0, 0);
    STAGE(1, 32768);
    asm volatile("s_waitcnt vmcnt(4)" ::: "memory");
    asm volatile("s_barrier" ::: "memory");

#pragma unroll
    for (int kt = 0; kt < 16; ++kt) {
        const int bufbase = (kt & 1) ? 32768 : 0;
        const char* As = smem + bufbase;
        const char* Bs = As + 16384;

        short8 af[8], bfr[4];
#pragma unroll
        for (int fn = 0; fn < 4; ++fn)
            bfr[fn] = *(const short8*)(Bs + wn * 4096 + fn * 1024 + C);
#pragma unroll
        for (int fm = 0; fm < 8; ++fm)
            af[fm] = *(const short8*)(As + wm * 8192 + fm * 1024 + C);

        __builtin_amdgcn_s_setprio(1);
#pragma unroll
        for (int fm = 0; fm < 4; ++fm)
#pragma unroll
            for (int fn = 0; fn < 4; ++fn)
                acc[fm][fn] = __builtin_amdgcn_mfma_f32_16x16x32_bf16(af[fm], bfr[fn], acc[fm][fn], 0, 0, 0);
        __builtin_amdgcn_s_setprio(0);

        if (kt < 14) {
            // all my LDS reads done -> barrier -> buffer is dead, refill with kt+2
            asm volatile("s_waitcnt lgkmcnt(0)" ::: "memory");
            asm volatile("s_barrier" ::: "memory");
            STAGE(kt + 2, bufbase);
        }

        __builtin_amdgcn_s_setprio(1);
#pragma unroll
        for (int fm = 4; fm < 8; ++fm)
#pragma unroll
            for (int fn = 0; fn < 4; ++fn)
                acc[fm][fn] = __builtin_amdgcn_mfma_f32_16x16x32_bf16(af[fm], bfr[fn], acc[fm][fn], 0, 0, 0);
        __builtin_amdgcn_s_setprio(0);

        if (kt < 14) {
            // wait kt+1's 4 loads (kt+2's 4 remain in flight across the barrier)
            asm volatile("s_waitcnt vmcnt(4)" ::: "memory");
            asm volatile("s_barrier" ::: "memory");
        } else if (kt == 14) {
            asm volatile("s_waitcnt vmcnt(0)" ::: "memory");
            asm volatile("s_barrier" ::: "memory");
        }
    }

    // ---- register-only LN2 epilogue (all 8 waves, no LDS, no barriers) ----
    float g2v[2], b2v[2];
#pragma unroll
    for (int fg = 0; fg < 2; ++fg) {
        int h = t * 128 + wn * 32 + fg * 16 + l15;
        g2v[fg] = g2[h];
        b2v[fg] = b2[h];
    }
#pragma unroll
    for (int fm = 0; fm < 8; ++fm) {
#pragma unroll
        for (int r = 0; r < 4; ++r) {
            int m = wm * 128 + fm * 16 + q * 4 + r;
            int rg = R0 + m;
            int b = (rg >= P) ? 1 : 0;
            int p = rg - b * P;
            int i = ii[p], j = jj[p];
            float mu = mu2[rg], iv = inv2[rg];
            const float* lp = ln1 + (size_t)(b * S + j) * H + t * 128 + wn * 32;
            const float* gp = G1 + (size_t)(b * S + i) * H + t * 128 + wn * 32;
            const float* bp = B1 + (size_t)(b * S + i) * H + t * 128 + wn * 32;
            float* op = out + (size_t)rg * H + t * 128 + wn * 32;
#pragma unroll
            for (int fg = 0; fg < 2; ++fg) {
                int c = fg * 16 + l15;
                float s = (lp[c] * gp[c] + bp[c] - mu) * iv;
                float G2v = acc[fm][fg][r] + g2v[fg];
                float B2v = acc[fm][fg + 2][r] + b2v[fg];
                op[c] = s * G2v + B2v;
            }
        }
    }
}

// ---------------- launcher ----------------
extern "C" void kernel_launch(void* const* d_in, const int* in_sizes, int n_in,
                              void* d_out, int out_size, void* d_ws, size_t ws_size,
                              hipStream_t stream) {
    const float* x = (const float*)d_in[0];
    const float* mask = (const float*)d_in[1];
    const float* lamtha = (const float*)d_in[2];
    const float* Wg1 = (const float*)d_in[3];
    const float* Wb1 = (const float*)d_in[4];
    const float* g1 = (const float*)d_in[5];
    const float* b1 = (const float*)d_in[6];
    const float* Wg2 = (const float*)d_in[7];
    const float* Wb2 = (const float*)d_in[8];
    const float* g2 = (const float*)d_in[9];
    const float* b2 = (const float*)d_in[10];
    float* out = (float*)d_out;

    char* ws = (char*)d_ws;
    float* seq = (float*)(ws + OFF_SEQ);
    float* csum = (float*)(ws + OFF_CSUM);
    float* ln1 = (float*)(ws + OFF_LN1);
    float* G1 = (float*)(ws + OFF_G1);
    float* B1 = (float*)(ws + OFF_B1);
    bf16* wcatT = (bf16*)(ws + OFF_WCAT);
    unsigned short* iiA = (unsigned short*)(ws + OFF_II);
    unsigned short* jjA = (unsigned short*)(ws + OFF_JJ);
    float* mu2 = (float*)(ws + OFF_MU2);
    float* inv2 = (float*)(ws + OFF_INV2);
    bf16* inner = (bf16*)(ws + OFF_INNER);
    float* tot = (float*)(ws + OFF_INNER);   // overlay; consumed before inner is written

    static bool attr_set = false;
    if (!attr_set) {
        hipFuncSetAttribute((const void*)gemm_kernel,
                            hipFuncAttributeMaxDynamicSharedMemorySize, 65536);
        attr_set = true;
    }

    hipLaunchKernelGGL(fusedA_kernel, dim3(1153), dim3(512), 0, stream,
                       x, mask, seq, tot, ln1, Wg2, Wb2, wcatT, iiA, jjA);
    hipLaunchKernelGGL(fusedB_kernel, dim3(320), dim3(512), 0, stream,
                       seq, tot, csum, Wg1, Wb1, g1, b1, G1, B1);
    hipLaunchKernelGGL(inner_kernel, dim3(512), dim3(256), 0, stream,
                       seq, csum, lamtha, inner);
    hipLaunchKernelGGL(stats_kernel, dim3(16448), dim3(256), 0, stream,
                       ln1, G1, B1, iiA, jjA, mu2, inv2);
    hipLaunchKernelGGL(gemm_kernel, dim3(1028), dim3(512), 65536, stream,
                       inner, wcatT, g2, b2, ln1, G1, B1, iiA, jjA, mu2, inv2, out);
}

// Round 6
// 301.803 us; speedup vs baseline: 3.3901x; 3.3901x over previous
//
#include <hip/hip_runtime.h>
#include <hip/hip_bf16.h>

typedef __hip_bfloat16 bf16;
typedef short short8 __attribute__((ext_vector_type(8)));
typedef float floatx4 __attribute__((ext_vector_type(4)));

#define S 256
#define H 512
#define P 32896            // S*(S+1)/2
#define NROWS 65792        // B*P
#define NEGF -1e30f
#define EPSF 1e-12f

// ---------------- ws layout (bytes) ----------------
#define OFF_SEQ    0u          // f32 [B*S*H]
#define OFF_LN1    2129920u    // f32 [B*S*H]
#define OFF_G1     3178496u    // f32 [B*S*H]
#define OFF_B1     4227072u    // f32 [B*S*H]
#define OFF_WCAT   5275648u    // bf16 [1024*512]
#define OFF_II     6324224u    // u16 [P]
#define OFF_JJ     6390016u    // u16 [P]
#define OFF_MU2    6455808u    // f32 [NROWS]
#define OFF_INV2   6718976u    // f32 [NROWS]
#define OFF_INNER  6982144u    // bf16 [NROWS*H]
// (csum / tot removed: inner computes its own running sum)

// async 16B global->LDS (lane-linear dest: base + lane*16)
__device__ __forceinline__ void gld_lds16(const void* g, void* l) {
    __builtin_amdgcn_global_load_lds(
        (const __attribute__((address_space(1))) void*)g,
        (__attribute__((address_space(3))) void*)l, 16, 0, 0);
}

// ---------------- fused A: seq+scan1+LN1 (blocks 0..63) | prep (64..1152) ----------------
// prep: wcatT row (n) interleave at 64-col granularity: GEMM htile t
// (wcatT rows [t*128, t*128+128)) holds G2 cols [t*64, t*64+64) at local rows
// 0..63 and the MATCHING B2 cols at local rows 64..127 -> register-only LN2
// epilogue in gemm (each wave owns matching G2/B2 fragments). [R4-verified pair]
__global__ __launch_bounds__(512) void fusedA_kernel(
    const float* __restrict__ x, const float* __restrict__ mask,
    float* __restrict__ seq, float* __restrict__ ln1,
    const float* __restrict__ Wg2, const float* __restrict__ Wb2,
    bf16* __restrict__ wcatT,
    unsigned short* __restrict__ ii, unsigned short* __restrict__ jj) {
    __shared__ float part[8][8][2];
    __shared__ float rstat[8][2];
    if (blockIdx.x < 64) {
        // ---- seq + fused LN1 (8 s-rows per block) ----
        int b = blockIdx.x >> 5, sc = blockIdx.x & 31, h = threadIdx.x;
        int wave = h >> 6, lane = h & 63;
        int s0 = sc * 8;
        float v[8];
#pragma unroll
        for (int t = 0; t < 8; ++t) {
            int s = s0 + t;
            v[t] = x[(size_t)(b * S + s) * H + h] + (1.0f - mask[b * S + s]) * (-1000.0f);
            seq[(size_t)(b * S + s) * H + h] = v[t];
        }
#pragma unroll
        for (int t = 0; t < 8; ++t) {
            float s = v[t], q = v[t] * v[t];
            for (int o = 1; o < 64; o <<= 1) { s += __shfl_xor(s, o); q += __shfl_xor(q, o); }
            if (lane == 0) { part[wave][t][0] = s; part[wave][t][1] = q; }
        }
        __syncthreads();
        if (h < 16) {
            int row = h >> 1, st = h & 1;
            float a = 0.0f;
#pragma unroll
            for (int w = 0; w < 8; ++w) a += part[w][row][st];
            rstat[row][st] = a;
        }
        __syncthreads();
#pragma unroll
        for (int t = 0; t < 8; ++t) {
            float m = rstat[t][0] * (1.0f / 512.0f);
            float var = rstat[t][1] * (1.0f / 512.0f) - m * m;
            var = var < 0.0f ? 0.0f : var;
            float inv = rsqrtf(var + EPSF);
            ln1[(size_t)(b * S + s0 + t) * H + h] = (v[t] - m) * inv;
        }
    } else {
        int n = blockIdx.x - 64;
        if (n < 1024) {
            int k = threadIdx.x;
            int tt = n >> 7, c = n & 127;
            int h = tt * 64 + (c & 63);
            float v = (c < 64) ? Wg2[(size_t)k * H + h] : Wb2[(size_t)k * H + h];
            wcatT[(size_t)n * H + k] = __float2bfloat16(v);
        } else {
            int p = (n - 1024) * 512 + threadIdx.x;
            if (p >= P) return;
            float disc = 513.0f * 513.0f - 8.0f * (float)p;
            int i = (int)((513.0f - sqrtf(disc)) * 0.5f);
            i = i < 0 ? 0 : (i > S - 1 ? S - 1 : i);
            while (i > 0 && (i * S - i * (i - 1) / 2) > p) --i;
            while (i < S - 1 && ((i + 1) * S - (i + 1) * i / 2) <= p) ++i;
            int off = i * S - i * (i - 1) / 2;
            ii[p] = (unsigned short)i;
            jj[p] = (unsigned short)(i + (p - off));
        }
    }
}

// ---------------- G1/B1 = bias + seq @ W1 ----------------
// grid (128, 2) x 256 thr: 4 s-rows per block, 2 h-columns per thread.
// Per k-quad: 4 LDS b128 broadcasts feed 32 FMAs (2x the old FMA/DS ratio);
// W read coalesced (2 dwords/thread/k). No scan2 / csum anywhere.
__global__ __launch_bounds__(256) void g1b1_kernel(
    const float* __restrict__ seq, const float* __restrict__ Wg1, const float* __restrict__ Wb1,
    const float* __restrict__ g1, const float* __restrict__ b1,
    float* __restrict__ G1, float* __restrict__ B1) {
    __shared__ float rowbuf[4][H];
    int grp = blockIdx.x;   // 0..127
    int mat = blockIdx.y;   // 0..1
    int tid = threadIdx.x;
    int h0 = tid, h1 = tid + 256;
    int r0 = grp * 4;
#pragma unroll
    for (int r = 0; r < 4; ++r) {
        rowbuf[r][h0] = seq[(size_t)(r0 + r) * H + h0];
        rowbuf[r][h1] = seq[(size_t)(r0 + r) * H + h1];
    }
    __syncthreads();
    const float* W = mat ? Wb1 : Wg1;
    float acc[4][2] = {{0, 0}, {0, 0}, {0, 0}, {0, 0}};
#pragma unroll 2
    for (int k4 = 0; k4 < 128; ++k4) {
        float4 a0 = ((const float4*)rowbuf[0])[k4];
        float4 a1 = ((const float4*)rowbuf[1])[k4];
        float4 a2 = ((const float4*)rowbuf[2])[k4];
        float4 a3 = ((const float4*)rowbuf[3])[k4];
        float w00 = W[(size_t)(k4 * 4 + 0) * H + h0], w01 = W[(size_t)(k4 * 4 + 0) * H + h1];
        float w10 = W[(size_t)(k4 * 4 + 1) * H + h0], w11 = W[(size_t)(k4 * 4 + 1) * H + h1];
        float w20 = W[(size_t)(k4 * 4 + 2) * H + h0], w21 = W[(size_t)(k4 * 4 + 2) * H + h1];
        float w30 = W[(size_t)(k4 * 4 + 3) * H + h0], w31 = W[(size_t)(k4 * 4 + 3) * H + h1];
        acc[0][0] += a0.x * w00 + a0.y * w10 + a0.z * w20 + a0.w * w30;
        acc[0][1] += a0.x * w01 + a0.y * w11 + a0.z * w21 + a0.w * w31;
        acc[1][0] += a1.x * w00 + a1.y * w10 + a1.z * w20 + a1.w * w30;
        acc[1][1] += a1.x * w01 + a1.y * w11 + a1.z * w21 + a1.w * w31;
        acc[2][0] += a2.x * w00 + a2.y * w10 + a2.z * w20 + a2.w * w30;
        acc[2][1] += a2.x * w01 + a2.y * w11 + a2.z * w21 + a2.w * w31;
        acc[3][0] += a3.x * w00 + a3.y * w10 + a3.z * w20 + a3.w * w30;
        acc[3][1] += a3.x * w01 + a3.y * w11 + a3.z * w21 + a3.w * w31;
    }
    float bias0 = (mat ? b1 : g1)[h0];
    float bias1 = (mat ? b1 : g1)[h1];
    float* dst = mat ? B1 : G1;
#pragma unroll
    for (int r = 0; r < 4; ++r) {
        dst[(size_t)(r0 + r) * H + h0] = acc[r][0] + bias0;
        dst[(size_t)(r0 + r) * H + h1] = acc[r][1] + bias1;
    }
}

// ---------------- inner[p][h] = lam*mean + (1-lam)*max (bf16x2, balanced) ----------------
// Running sum replaces csum (identical quantity, f32 rounding delta ~1e-3):
// half the load traffic of the csum version. j-loop unrolled x4.
__global__ __launch_bounds__(256) void inner_kernel(
    const float* __restrict__ seq, const float* __restrict__ lamtha,
    bf16* __restrict__ inner) {
    int id = blockIdx.x;
    int t = id & 255, b = id >> 8;
    int i = b ? (255 - t) : t;
    int h2 = threadIdx.x;                 // float2 index, 0..255
    float2 lam = ((const float2*)lamtha)[h2];
    float2 oml = {1.0f - lam.x, 1.0f - lam.y};
    const float2* seqb = (const float2*)(seq + (size_t)b * S * H);
    float2 mrun = {NEGF, NEGF};
    float2 srun = {0.0f, 0.0f};
    size_t base = (size_t)b * P + (size_t)(i * S - i * (i - 1) / 2);
    __hip_bfloat162* dst = (__hip_bfloat162*)inner;
    int j = i;
#define INNER_STEP(vv, jx)                                                 \
    {                                                                      \
        srun.x += vv.x;                                                    \
        srun.y += vv.y;                                                    \
        mrun.x = fmaxf(mrun.x, vv.x);                                      \
        mrun.y = fmaxf(mrun.y, vv.y);                                      \
        float rl = 1.0f / (float)((jx) - i + 1);                           \
        float mx = srun.x * rl;                                            \
        float my = srun.y * rl;                                            \
        __hip_bfloat162 o;                                                 \
        o.x = __float2bfloat16(lam.x * mx + oml.x * mrun.x);               \
        o.y = __float2bfloat16(lam.y * my + oml.y * mrun.y);               \
        dst[(base + (size_t)((jx) - i)) * 256 + h2] = o;                   \
    }
    for (; j + 4 <= S; j += 4) {
        float2 v0 = seqb[(j + 0) * 256 + h2];
        float2 v1 = seqb[(j + 1) * 256 + h2];
        float2 v2 = seqb[(j + 2) * 256 + h2];
        float2 v3 = seqb[(j + 3) * 256 + h2];
        INNER_STEP(v0, j + 0)
        INNER_STEP(v1, j + 1)
        INNER_STEP(v2, j + 2)
        INNER_STEP(v3, j + 3)
    }
    for (; j < S; ++j) {
        float2 v = seqb[j * 256 + h2];
        INNER_STEP(v, j)
    }
#undef INNER_STEP
}

// ---------------- LN2 row stats: wave per pair-row (float4 loads) ----------------
__global__ void stats_kernel(const float* __restrict__ ln1, const float* __restrict__ G1,
                             const float* __restrict__ B1,
                             const unsigned short* __restrict__ ii,
                             const unsigned short* __restrict__ jj,
                             float* __restrict__ mu2, float* __restrict__ inv2) {
    int r = blockIdx.x * 4 + (threadIdx.x >> 6);
    int lane = threadIdx.x & 63;
    int b = (r >= P) ? 1 : 0;
    int p = r - b * P;
    int i = ii[p], j = jj[p];
    const float4* lp = (const float4*)(ln1 + (size_t)(b * S + j) * H);
    const float4* gp = (const float4*)(G1 + (size_t)(b * S + i) * H);
    const float4* bp = (const float4*)(B1 + (size_t)(b * S + i) * H);
    float sum = 0.0f, ss = 0.0f;
#pragma unroll
    for (int t = 0; t < 2; ++t) {
        int idx = t * 64 + lane;
        float4 a = lp[idx], g = gp[idx], bb = bp[idx];
        float v0 = a.x * g.x + bb.x, v1 = a.y * g.y + bb.y;
        float v2 = a.z * g.z + bb.z, v3 = a.w * g.w + bb.w;
        sum += (v0 + v1) + (v2 + v3);
        ss += (v0 * v0 + v1 * v1) + (v2 * v2 + v3 * v3);
    }
    for (int o = 1; o < 64; o <<= 1) { sum += __shfl_xor(sum, o); ss += __shfl_xor(ss, o); }
    if (lane == 0) {
        float m = sum * (1.0f / 512.0f);
        float var = ss * (1.0f / 512.0f) - m * m;
        var = var < 0.0f ? 0.0f : var;
        mu2[r] = m;
        inv2[r] = rsqrtf(var + EPSF);
    }
}

// ---------------- fused GEMM (inner @ [Wg2|Wb2]) + LN2 epilogue ----------------
// EXACT R3 kernel (measured 97-98 us, MfmaUtil ~29, FETCH ~48 MB, 0 bank conf).
// 128x128 tile, 4 waves (2M x 2N), BK=64, LDS double-buffered (64 KB)
// -> 2 blocks/CU. Counted-vmcnt pipeline; register-only LN2 epilogue.
// Grid 4112 = 514 row-panels x 8 htiles; panel's 8 htiles share one XCD.
__global__ __launch_bounds__(256, 2) void gemm_kernel(
    const bf16* __restrict__ inner, const bf16* __restrict__ wcatT,
    const float* __restrict__ g2, const float* __restrict__ b2,
    const float* __restrict__ ln1, const float* __restrict__ G1, const float* __restrict__ B1,
    const unsigned short* __restrict__ ii, const unsigned short* __restrict__ jj,
    const float* __restrict__ mu2, const float* __restrict__ inv2,
    float* __restrict__ out) {
    extern __shared__ __align__(16) char smem[];   // 65536: 2 bufs x (A 16K | B 16K)

    const int tid = threadIdx.x;
    const int wave = tid >> 6, lane = tid & 63;
    const int q = lane >> 4, l15 = lane & 15;
    const int wm = wave & 1, wn = wave >> 1;       // wm 0..1, wn 0..1

    const int id = blockIdx.x;
    int rb, t;
    if (id < 4096) { rb = (id >> 6) * 8 + (id & 7); t = (id >> 3) & 7; }
    else           { int w = id - 4096; rb = 512 + (w & 1); t = w >> 1; }
    const int R0 = rb * 128;

    const int srow = tid >> 3;                    // 0..31
    const int sx8 = ((tid & 7) ^ (srow & 7)) * 8;
    const bf16* const Ag = inner + (size_t)(R0 + srow) * H + sx8;
    const bf16* const Bg = wcatT + (size_t)(t * 128 + srow) * H + sx8;

    char* const A0 = smem;
    char* const B0 = smem + 16384;
    char* const A1 = smem + 32768;
    char* const B1s = smem + 49152;

    floatx4 acc[4][4];
#pragma unroll
    for (int a = 0; a < 4; ++a)
#pragma unroll
        for (int c = 0; c < 4; ++c) acc[a][c] = (floatx4){0.f, 0.f, 0.f, 0.f};

    auto STAGE = [&](int kt, char* Ad, char* Bd) {
#pragma unroll
        for (int i2 = 0; i2 < 4; ++i2)
            gld_lds16(Ag + (size_t)i2 * 32 * H + kt * 64, Ad + i2 * 4096 + wave * 1024);
#pragma unroll
        for (int i2 = 0; i2 < 4; ++i2)
            gld_lds16(Bg + (size_t)i2 * 32 * H + kt * 64, Bd + i2 * 4096 + wave * 1024);
    };

    STAGE(0, A0, B0);
    STAGE(1, A1, B1s);
    asm volatile("s_waitcnt vmcnt(8)" ::: "memory");
    asm volatile("s_barrier" ::: "memory");

#pragma unroll
    for (int kt = 0; kt < 8; ++kt) {
        char* const As = (kt & 1) ? A1 : A0;
        char* const Bs = (kt & 1) ? B1s : B0;

        short8 bfr[4][2], af[4][2];
#pragma unroll
        for (int ks = 0; ks < 2; ++ks) {
#pragma unroll
            for (int fn = 0; fn < 4; ++fn) {
                int nr = (fn < 2 ? wn * 32 + fn * 16 : 64 + wn * 32 + (fn - 2) * 16) + l15;
                bfr[fn][ks] = *(const short8*)(Bs + nr * 128 + (((ks * 4 + q) ^ (l15 & 7)) << 4));
            }
#pragma unroll
            for (int fm = 0; fm < 4; ++fm) {
                int mr = wm * 64 + fm * 16 + l15;
                af[fm][ks] = *(const short8*)(As + mr * 128 + (((ks * 4 + q) ^ (l15 & 7)) << 4));
            }
        }

        __builtin_amdgcn_s_setprio(1);
#pragma unroll
        for (int fm = 0; fm < 4; ++fm)
#pragma unroll
            for (int fn = 0; fn < 4; ++fn)
                acc[fm][fn] = __builtin_amdgcn_mfma_f32_16x16x32_bf16(af[fm][0], bfr[fn][0], acc[fm][fn], 0, 0, 0);
        __builtin_amdgcn_s_setprio(0);

        if (kt < 6) {
            asm volatile("s_waitcnt lgkmcnt(0)" ::: "memory");
            asm volatile("s_barrier" ::: "memory");
            STAGE(kt + 2, As, Bs);
        }

        __builtin_amdgcn_s_setprio(1);
#pragma unroll
        for (int fm = 0; fm < 4; ++fm)
#pragma unroll
            for (int fn = 0; fn < 4; ++fn)
                acc[fm][fn] = __builtin_amdgcn_mfma_f32_16x16x32_bf16(af[fm][1], bfr[fn][1], acc[fm][fn], 0, 0, 0);
        __builtin_amdgcn_s_setprio(0);

        if (kt < 6) {
            asm volatile("s_waitcnt vmcnt(8)" ::: "memory");
            asm volatile("s_barrier" ::: "memory");
        } else if (kt == 6) {
            asm volatile("s_waitcnt vmcnt(0)" ::: "memory");
            asm volatile("s_barrier" ::: "memory");
        }
    }

    // ---- register-only LN2 epilogue (all 4 waves, no LDS, no barriers) ----
    float g2v[2], b2v[2];
#pragma unroll
    for (int fg = 0; fg < 2; ++fg) {
        int h = t * 64 + wn * 32 + fg * 16 + l15;
        g2v[fg] = g2[h];
        b2v[fg] = b2[h];
    }
#pragma unroll
    for (int fm = 0; fm < 4; ++fm) {
#pragma unroll
        for (int r = 0; r < 4; ++r) {
            int m = wm * 64 + fm * 16 + q * 4 + r;
            int rg = R0 + m;
            int b = (rg >= P) ? 1 : 0;
            int p = rg - b * P;
            int i = ii[p], j = jj[p];
            float mu = mu2[rg], iv = inv2[rg];
            const float* lp = ln1 + (size_t)(b * S + j) * H + t * 64 + wn * 32;
            const float* gp = G1 + (size_t)(b * S + i) * H + t * 64 + wn * 32;
            const float* bp = B1 + (size_t)(b * S + i) * H + t * 64 + wn * 32;
            float* op = out + (size_t)rg * H + t * 64 + wn * 32;
#pragma unroll
            for (int fg = 0; fg < 2; ++fg) {
                int c = fg * 16 + l15;
                float s = (lp[c] * gp[c] + bp[c] - mu) * iv;
                float G2v = acc[fm][fg][r] + g2v[fg];
                float B2v = acc[fm][fg + 2][r] + b2v[fg];
                op[c] = s * G2v + B2v;
            }
        }
    }
}

// ---------------- launcher ----------------
extern "C" void kernel_launch(void* const* d_in, const int* in_sizes, int n_in,
                              void* d_out, int out_size, void* d_ws, size_t ws_size,
                              hipStream_t stream) {
    const float* x = (const float*)d_in[0];
    const float* mask = (const float*)d_in[1];
    const float* lamtha = (const float*)d_in[2];
    const float* Wg1 = (const float*)d_in[3];
    const float* Wb1 = (const float*)d_in[4];
    const float* g1 = (const float*)d_in[5];
    const float* b1 = (const float*)d_in[6];
    const float* Wg2 = (const float*)d_in[7];
    const float* Wb2 = (const float*)d_in[8];
    const float* g2 = (const float*)d_in[9];
    const float* b2 = (const float*)d_in[10];
    float* out = (float*)d_out;

    char* ws = (char*)d_ws;
    float* seq = (float*)(ws + OFF_SEQ);
    float* ln1 = (float*)(ws + OFF_LN1);
    float* G1 = (float*)(ws + OFF_G1);
    float* B1 = (float*)(ws + OFF_B1);
    bf16* wcatT = (bf16*)(ws + OFF_WCAT);
    unsigned short* iiA = (unsigned short*)(ws + OFF_II);
    unsigned short* jjA = (unsigned short*)(ws + OFF_JJ);
    float* mu2 = (float*)(ws + OFF_MU2);
    float* inv2 = (float*)(ws + OFF_INV2);
    bf16* inner = (bf16*)(ws + OFF_INNER);

    static bool attr_set = false;
    if (!attr_set) {
        hipFuncSetAttribute((const void*)gemm_kernel,
                            hipFuncAttributeMaxDynamicSharedMemorySize, 65536);
        attr_set = true;
    }

    hipLaunchKernelGGL(fusedA_kernel, dim3(1153), dim3(512), 0, stream,
                       x, mask, seq, ln1, Wg2, Wb2, wcatT, iiA, jjA);
    hipLaunchKernelGGL(g1b1_kernel, dim3(128, 2), dim3(256), 0, stream,
                       seq, Wg1, Wb1, g1, b1, G1, B1);
    hipLaunchKernelGGL(inner_kernel, dim3(512), dim3(256), 0, stream,
                       seq, lamtha, inner);
    hipLaunchKernelGGL(stats_kernel, dim3(16448), dim3(256), 0, stream,
                       ln1, G1, B1, iiA, jjA, mu2, inv2);
    hipLaunchKernelGGL(gemm_kernel, dim3(4112), dim3(256), 65536, stream,
                       inner, wcatT, g2, b2, ln1, G1, B1, iiA, jjA, mu2, inv2, out);
}

// Round 7
// 301.485 us; speedup vs baseline: 3.3937x; 1.0011x over previous
//
#include <hip/hip_runtime.h>
#include <hip/hip_bf16.h>

typedef __hip_bfloat16 bf16;
typedef short short8 __attribute__((ext_vector_type(8)));
typedef float floatx4 __attribute__((ext_vector_type(4)));

#define S 256
#define H 512
#define P 32896            // S*(S+1)/2
#define NROWS 65792        // B*P
#define NEGF -1e30f
#define EPSF 1e-12f

// ---------------- ws layout (bytes) ----------------
#define OFF_LN1    2129920u    // f32 [B*S*H]
#define OFF_G1     3178496u    // f32 [B*S*H]
#define OFF_B1     4227072u    // f32 [B*S*H]
#define OFF_WCAT   5275648u    // bf16 [1024*512]
#define OFF_II     6324224u    // u16 [P]
#define OFF_JJ     6390016u    // u16 [P]
#define OFF_MU2    6455808u    // f32 [NROWS]
#define OFF_INV2   6718976u    // f32 [NROWS]
#define OFF_INNER  6982144u    // bf16 [NROWS*H]
// (seq / csum / tot removed: consumers compute seq = x + (1-mask)*(-1000) inline)

// async 16B global->LDS (lane-linear dest: base + lane*16)
__device__ __forceinline__ void gld_lds16(const void* g, void* l) {
    __builtin_amdgcn_global_load_lds(
        (const __attribute__((address_space(1))) void*)g,
        (__attribute__((address_space(3))) void*)l, 16, 0, 0);
}

// ---------------- fused A: LN1 (blocks 0..63) | prep (64..1152) ----------------
// prep: wcatT row (n) interleave at 64-col granularity: GEMM htile t
// (wcatT rows [t*128, t*128+128)) holds G2 cols [t*64, t*64+64) at local rows
// 0..63 and the MATCHING B2 cols at local rows 64..127 -> register-only LN2
// epilogue in gemm (each wave owns matching G2/B2 fragments). [R4-verified pair]
__global__ __launch_bounds__(512) void fusedA_kernel(
    const float* __restrict__ x, const float* __restrict__ mask,
    float* __restrict__ ln1,
    const float* __restrict__ Wg2, const float* __restrict__ Wb2,
    bf16* __restrict__ wcatT,
    unsigned short* __restrict__ ii, unsigned short* __restrict__ jj) {
    __shared__ float part[8][8][2];
    __shared__ float rstat[8][2];
    if (blockIdx.x < 64) {
        // ---- LN1 (8 s-rows per block); seq computed inline, not materialized ----
        int b = blockIdx.x >> 5, sc = blockIdx.x & 31, h = threadIdx.x;
        int wave = h >> 6, lane = h & 63;
        int s0 = sc * 8;
        float v[8];
#pragma unroll
        for (int t = 0; t < 8; ++t) {
            int s = s0 + t;
            v[t] = x[(size_t)(b * S + s) * H + h] + (1.0f - mask[b * S + s]) * (-1000.0f);
        }
#pragma unroll
        for (int t = 0; t < 8; ++t) {
            float s = v[t], q = v[t] * v[t];
            for (int o = 1; o < 64; o <<= 1) { s += __shfl_xor(s, o); q += __shfl_xor(q, o); }
            if (lane == 0) { part[wave][t][0] = s; part[wave][t][1] = q; }
        }
        __syncthreads();
        if (h < 16) {
            int row = h >> 1, st = h & 1;
            float a = 0.0f;
#pragma unroll
            for (int w = 0; w < 8; ++w) a += part[w][row][st];
            rstat[row][st] = a;
        }
        __syncthreads();
#pragma unroll
        for (int t = 0; t < 8; ++t) {
            float m = rstat[t][0] * (1.0f / 512.0f);
            float var = rstat[t][1] * (1.0f / 512.0f) - m * m;
            var = var < 0.0f ? 0.0f : var;
            float inv = rsqrtf(var + EPSF);
            ln1[(size_t)(b * S + s0 + t) * H + h] = (v[t] - m) * inv;
        }
    } else {
        int n = blockIdx.x - 64;
        if (n < 1024) {
            int k = threadIdx.x;
            int tt = n >> 7, c = n & 127;
            int h = tt * 64 + (c & 63);
            float v = (c < 64) ? Wg2[(size_t)k * H + h] : Wb2[(size_t)k * H + h];
            wcatT[(size_t)n * H + k] = __float2bfloat16(v);
        } else {
            int p = (n - 1024) * 512 + threadIdx.x;
            if (p >= P) return;
            float disc = 513.0f * 513.0f - 8.0f * (float)p;
            int i = (int)((513.0f - sqrtf(disc)) * 0.5f);
            i = i < 0 ? 0 : (i > S - 1 ? S - 1 : i);
            while (i > 0 && (i * S - i * (i - 1) / 2) > p) --i;
            while (i < S - 1 && ((i + 1) * S - (i + 1) * i / 2) <= p) ++i;
            int off = i * S - i * (i - 1) / 2;
            ii[p] = (unsigned short)i;
            jj[p] = (unsigned short)(i + (p - off));
        }
    }
}

// ---------------- G1/B1 = bias + seq @ W1 (seq computed inline) ----------------
// grid (128, 2) x 256 thr: 4 s-rows per block, 2 h-columns per thread.
// Per k-quad: 4 LDS b128 broadcasts feed 32 FMAs; W read coalesced.
__global__ __launch_bounds__(256) void g1b1_kernel(
    const float* __restrict__ x, const float* __restrict__ mask,
    const float* __restrict__ Wg1, const float* __restrict__ Wb1,
    const float* __restrict__ g1, const float* __restrict__ b1,
    float* __restrict__ G1, float* __restrict__ B1) {
    __shared__ float rowbuf[4][H];
    int grp = blockIdx.x;   // 0..127
    int mat = blockIdx.y;   // 0..1
    int tid = threadIdx.x;
    int h0 = tid, h1 = tid + 256;
    int r0 = grp * 4;
#pragma unroll
    for (int r = 0; r < 4; ++r) {
        int row = r0 + r;
        float add = (1.0f - mask[row]) * (-1000.0f);
        rowbuf[r][h0] = x[(size_t)row * H + h0] + add;
        rowbuf[r][h1] = x[(size_t)row * H + h1] + add;
    }
    __syncthreads();
    const float* W = mat ? Wb1 : Wg1;
    float acc[4][2] = {{0, 0}, {0, 0}, {0, 0}, {0, 0}};
#pragma unroll 2
    for (int k4 = 0; k4 < 128; ++k4) {
        float4 a0 = ((const float4*)rowbuf[0])[k4];
        float4 a1 = ((const float4*)rowbuf[1])[k4];
        float4 a2 = ((const float4*)rowbuf[2])[k4];
        float4 a3 = ((const float4*)rowbuf[3])[k4];
        float w00 = W[(size_t)(k4 * 4 + 0) * H + h0], w01 = W[(size_t)(k4 * 4 + 0) * H + h1];
        float w10 = W[(size_t)(k4 * 4 + 1) * H + h0], w11 = W[(size_t)(k4 * 4 + 1) * H + h1];
        float w20 = W[(size_t)(k4 * 4 + 2) * H + h0], w21 = W[(size_t)(k4 * 4 + 2) * H + h1];
        float w30 = W[(size_t)(k4 * 4 + 3) * H + h0], w31 = W[(size_t)(k4 * 4 + 3) * H + h1];
        acc[0][0] += a0.x * w00 + a0.y * w10 + a0.z * w20 + a0.w * w30;
        acc[0][1] += a0.x * w01 + a0.y * w11 + a0.z * w21 + a0.w * w31;
        acc[1][0] += a1.x * w00 + a1.y * w10 + a1.z * w20 + a1.w * w30;
        acc[1][1] += a1.x * w01 + a1.y * w11 + a1.z * w21 + a1.w * w31;
        acc[2][0] += a2.x * w00 + a2.y * w10 + a2.z * w20 + a2.w * w30;
        acc[2][1] += a2.x * w01 + a2.y * w11 + a2.z * w21 + a2.w * w31;
        acc[3][0] += a3.x * w00 + a3.y * w10 + a3.z * w20 + a3.w * w30;
        acc[3][1] += a3.x * w01 + a3.y * w11 + a3.z * w21 + a3.w * w31;
    }
    float bias0 = (mat ? b1 : g1)[h0];
    float bias1 = (mat ? b1 : g1)[h1];
    float* dst = mat ? B1 : G1;
#pragma unroll
    for (int r = 0; r < 4; ++r) {
        dst[(size_t)(r0 + r) * H + h0] = acc[r][0] + bias0;
        dst[(size_t)(r0 + r) * H + h1] = acc[r][1] + bias1;
    }
}

// ---------------- co-scheduled: inner (even ids) | LN2 row stats (odd ids) ----------------
// inner: running sum/max over seq = x + maskadd (LDS broadcast table); x4 unroll.
// stats: one block per (b,i); G1[i]/B1[i] pinned in REGISTERS (8 f32/lane each),
// stream ln1[j] for j>=i -> 395 MB/pass (old per-pair re-read) becomes ~140 MB.
// Both use the same balanced (b,i) pairing; 1024 blocks = 4/CU co-resident, so
// inner's store-heavy loop overlaps stats' load-heavy loop on each CU.
__global__ __launch_bounds__(256) void innerstats_kernel(
    const float* __restrict__ x, const float* __restrict__ mask,
    const float* __restrict__ lamtha,
    const float* __restrict__ ln1, const float* __restrict__ G1,
    const float* __restrict__ B1,
    bf16* __restrict__ inner, float* __restrict__ mu2, float* __restrict__ inv2) {
    __shared__ float maskadd[256];
    int id = blockIdx.x;
    int kind = id & 1, sub = id >> 1;
    int t = sub & 255, b = sub >> 8;
    int i = b ? (255 - t) : t;
    int tid = threadIdx.x;
    int off = i * S - i * (i - 1) / 2;

    if (kind == 0) {
        // ---- inner ----
        int h2 = tid;                 // float2 index, 0..255
        maskadd[tid] = (1.0f - mask[b * S + tid]) * (-1000.0f);
        __syncthreads();
        float2 lam = ((const float2*)lamtha)[h2];
        float2 oml = {1.0f - lam.x, 1.0f - lam.y};
        const float2* xb = (const float2*)(x + (size_t)b * S * H);
        float2 mrun = {NEGF, NEGF};
        float2 srun = {0.0f, 0.0f};
        size_t base = (size_t)b * P + (size_t)off;
        __hip_bfloat162* dst = (__hip_bfloat162*)inner;
        int j = i;
#define INNER_STEP(xx, jx)                                                 \
    {                                                                      \
        float ma = maskadd[jx];                                            \
        float vx = xx.x + ma, vy = xx.y + ma;                              \
        srun.x += vx;                                                      \
        srun.y += vy;                                                      \
        mrun.x = fmaxf(mrun.x, vx);                                        \
        mrun.y = fmaxf(mrun.y, vy);                                        \
        float rl = 1.0f / (float)((jx) - i + 1);                           \
        float mx = srun.x * rl;                                            \
        float my = srun.y * rl;                                            \
        __hip_bfloat162 o;                                                 \
        o.x = __float2bfloat16(lam.x * mx + oml.x * mrun.x);               \
        o.y = __float2bfloat16(lam.y * my + oml.y * mrun.y);               \
        dst[(base + (size_t)((jx) - i)) * 256 + h2] = o;                   \
    }
        for (; j + 4 <= S; j += 4) {
            float2 x0 = xb[(j + 0) * 256 + h2];
            float2 x1 = xb[(j + 1) * 256 + h2];
            float2 x2 = xb[(j + 2) * 256 + h2];
            float2 x3 = xb[(j + 3) * 256 + h2];
            INNER_STEP(x0, j + 0)
            INNER_STEP(x1, j + 1)
            INNER_STEP(x2, j + 2)
            INNER_STEP(x3, j + 3)
        }
        for (; j < S; ++j) {
            float2 xv = xb[j * 256 + h2];
            INNER_STEP(xv, j)
        }
#undef INNER_STEP
    } else {
        // ---- stats ----
        int wave = tid >> 6, lane = tid & 63;
        const float4* gp = (const float4*)(G1 + (size_t)(b * S + i) * H);
        const float4* bp = (const float4*)(B1 + (size_t)(b * S + i) * H);
        float4 ga = gp[lane * 2], gb = gp[lane * 2 + 1];
        float4 ba = bp[lane * 2], bb = bp[lane * 2 + 1];
        for (int j = i + wave; j < S; j += 4) {
            const float4* lp = (const float4*)(ln1 + (size_t)(b * S + j) * H);
            float4 a0 = lp[lane * 2], a1 = lp[lane * 2 + 1];
            float v0 = a0.x * ga.x + ba.x, v1 = a0.y * ga.y + ba.y;
            float v2 = a0.z * ga.z + ba.z, v3 = a0.w * ga.w + ba.w;
            float v4 = a1.x * gb.x + bb.x, v5 = a1.y * gb.y + bb.y;
            float v6 = a1.z * gb.z + bb.z, v7 = a1.w * gb.w + bb.w;
            float sum = ((v0 + v1) + (v2 + v3)) + ((v4 + v5) + (v6 + v7));
            float ss = ((v0 * v0 + v1 * v1) + (v2 * v2 + v3 * v3)) +
                       ((v4 * v4 + v5 * v5) + (v6 * v6 + v7 * v7));
            for (int o = 1; o < 64; o <<= 1) { sum += __shfl_xor(sum, o); ss += __shfl_xor(ss, o); }
            if (lane == 0) {
                int r = b * P + off + (j - i);
                float m = sum * (1.0f / 512.0f);
                float var = ss * (1.0f / 512.0f) - m * m;
                var = var < 0.0f ? 0.0f : var;
                mu2[r] = m;
                inv2[r] = rsqrtf(var + EPSF);
            }
        }
    }
}

// ---------------- fused GEMM (inner @ [Wg2|Wb2]) + LN2 epilogue ----------------
// EXACT R3/R6 kernel (measured 97-98 us, MfmaUtil ~29, FETCH ~48 MB, 0 bank conf).
// 128x128 tile, 4 waves (2M x 2N), BK=64, LDS double-buffered (64 KB)
// -> 2 blocks/CU. Counted-vmcnt pipeline; register-only LN2 epilogue.
// Grid 4112 = 514 row-panels x 8 htiles; panel's 8 htiles share one XCD.
__global__ __launch_bounds__(256, 2) void gemm_kernel(
    const bf16* __restrict__ inner, const bf16* __restrict__ wcatT,
    const float* __restrict__ g2, const float* __restrict__ b2,
    const float* __restrict__ ln1, const float* __restrict__ G1, const float* __restrict__ B1,
    const unsigned short* __restrict__ ii, const unsigned short* __restrict__ jj,
    const float* __restrict__ mu2, const float* __restrict__ inv2,
    float* __restrict__ out) {
    extern __shared__ __align__(16) char smem[];   // 65536: 2 bufs x (A 16K | B 16K)

    const int tid = threadIdx.x;
    const int wave = tid >> 6, lane = tid & 63;
    const int q = lane >> 4, l15 = lane & 15;
    const int wm = wave & 1, wn = wave >> 1;       // wm 0..1, wn 0..1

    const int id = blockIdx.x;
    int rb, t;
    if (id < 4096) { rb = (id >> 6) * 8 + (id & 7); t = (id >> 3) & 7; }
    else           { int w = id - 4096; rb = 512 + (w & 1); t = w >> 1; }
    const int R0 = rb * 128;

    const int srow = tid >> 3;                    // 0..31
    const int sx8 = ((tid & 7) ^ (srow & 7)) * 8;
    const bf16* const Ag = inner + (size_t)(R0 + srow) * H + sx8;
    const bf16* const Bg = wcatT + (size_t)(t * 128 + srow) * H + sx8;

    char* const A0 = smem;
    char* const B0 = smem + 16384;
    char* const A1 = smem + 32768;
    char* const B1s = smem + 49152;

    floatx4 acc[4][4];
#pragma unroll
    for (int a = 0; a < 4; ++a)
#pragma unroll
        for (int c = 0; c < 4; ++c) acc[a][c] = (floatx4){0.f, 0.f, 0.f, 0.f};

    auto STAGE = [&](int kt, char* Ad, char* Bd) {
#pragma unroll
        for (int i2 = 0; i2 < 4; ++i2)
            gld_lds16(Ag + (size_t)i2 * 32 * H + kt * 64, Ad + i2 * 4096 + wave * 1024);
#pragma unroll
        for (int i2 = 0; i2 < 4; ++i2)
            gld_lds16(Bg + (size_t)i2 * 32 * H + kt * 64, Bd + i2 * 4096 + wave * 1024);
    };

    STAGE(0, A0, B0);
    STAGE(1, A1, B1s);
    asm volatile("s_waitcnt vmcnt(8)" ::: "memory");
    asm volatile("s_barrier" ::: "memory");

#pragma unroll
    for (int kt = 0; kt < 8; ++kt) {
        char* const As = (kt & 1) ? A1 : A0;
        char* const Bs = (kt & 1) ? B1s : B0;

        short8 bfr[4][2], af[4][2];
#pragma unroll
        for (int ks = 0; ks < 2; ++ks) {
#pragma unroll
            for (int fn = 0; fn < 4; ++fn) {
                int nr = (fn < 2 ? wn * 32 + fn * 16 : 64 + wn * 32 + (fn - 2) * 16) + l15;
                bfr[fn][ks] = *(const short8*)(Bs + nr * 128 + (((ks * 4 + q) ^ (l15 & 7)) << 4));
            }
#pragma unroll
            for (int fm = 0; fm < 4; ++fm) {
                int mr = wm * 64 + fm * 16 + l15;
                af[fm][ks] = *(const short8*)(As + mr * 128 + (((ks * 4 + q) ^ (l15 & 7)) << 4));
            }
        }

        __builtin_amdgcn_s_setprio(1);
#pragma unroll
        for (int fm = 0; fm < 4; ++fm)
#pragma unroll
            for (int fn = 0; fn < 4; ++fn)
                acc[fm][fn] = __builtin_amdgcn_mfma_f32_16x16x32_bf16(af[fm][0], bfr[fn][0], acc[fm][fn], 0, 0, 0);
        __builtin_amdgcn_s_setprio(0);

        if (kt < 6) {
            asm volatile("s_waitcnt lgkmcnt(0)" ::: "memory");
            asm volatile("s_barrier" ::: "memory");
            STAGE(kt + 2, As, Bs);
        }

        __builtin_amdgcn_s_setprio(1);
#pragma unroll
        for (int fm = 0; fm < 4; ++fm)
#pragma unroll
            for (int fn = 0; fn < 4; ++fn)
                acc[fm][fn] = __builtin_amdgcn_mfma_f32_16x16x32_bf16(af[fm][1], bfr[fn][1], acc[fm][fn], 0, 0, 0);
        __builtin_amdgcn_s_setprio(0);

        if (kt < 6) {
            asm volatile("s_waitcnt vmcnt(8)" ::: "memory");
            asm volatile("s_barrier" ::: "memory");
        } else if (kt == 6) {
            asm volatile("s_waitcnt vmcnt(0)" ::: "memory");
            asm volatile("s_barrier" ::: "memory");
        }
    }

    // ---- register-only LN2 epilogue (all 4 waves, no LDS, no barriers) ----
    float g2v[2], b2v[2];
#pragma unroll
    for (int fg = 0; fg < 2; ++fg) {
        int h = t * 64 + wn * 32 + fg * 16 + l15;
        g2v[fg] = g2[h];
        b2v[fg] = b2[h];
    }
#pragma unroll
    for (int fm = 0; fm < 4; ++fm) {
#pragma unroll
        for (int r = 0; r < 4; ++r) {
            int m = wm * 64 + fm * 16 + q * 4 + r;
            int rg = R0 + m;
            int b = (rg >= P) ? 1 : 0;
            int p = rg - b * P;
            int i = ii[p], j = jj[p];
            float mu = mu2[rg], iv = inv2[rg];
            const float* lp = ln1 + (size_t)(b * S + j) * H + t * 64 + wn * 32;
            const float* gp = G1 + (size_t)(b * S + i) * H + t * 64 + wn * 32;
            const float* bp = B1 + (size_t)(b * S + i) * H + t * 64 + wn * 32;
            float* op = out + (size_t)rg * H + t * 64 + wn * 32;
#pragma unroll
            for (int fg = 0; fg < 2; ++fg) {
                int c = fg * 16 + l15;
                float s = (lp[c] * gp[c] + bp[c] - mu) * iv;
                float G2v = acc[fm][fg][r] + g2v[fg];
                float B2v = acc[fm][fg + 2][r] + b2v[fg];
                op[c] = s * G2v + B2v;
            }
        }
    }
}

// ---------------- launcher ----------------
extern "C" void kernel_launch(void* const* d_in, const int* in_sizes, int n_in,
                              void* d_out, int out_size, void* d_ws, size_t ws_size,
                              hipStream_t stream) {
    const float* x = (const float*)d_in[0];
    const float* mask = (const float*)d_in[1];
    const float* lamtha = (const float*)d_in[2];
    const float* Wg1 = (const float*)d_in[3];
    const float* Wb1 = (const float*)d_in[4];
    const float* g1 = (const float*)d_in[5];
    const float* b1 = (const float*)d_in[6];
    const float* Wg2 = (const float*)d_in[7];
    const float* Wb2 = (const float*)d_in[8];
    const float* g2 = (const float*)d_in[9];
    const float* b2 = (const float*)d_in[10];
    float* out = (float*)d_out;

    char* ws = (char*)d_ws;
    float* ln1 = (float*)(ws + OFF_LN1);
    float* G1 = (float*)(ws + OFF_G1);
    float* B1 = (float*)(ws + OFF_B1);
    bf16* wcatT = (bf16*)(ws + OFF_WCAT);
    unsigned short* iiA = (unsigned short*)(ws + OFF_II);
    unsigned short* jjA = (unsigned short*)(ws + OFF_JJ);
    float* mu2 = (float*)(ws + OFF_MU2);
    float* inv2 = (float*)(ws + OFF_INV2);
    bf16* inner = (bf16*)(ws + OFF_INNER);

    static bool attr_set = false;
    if (!attr_set) {
        hipFuncSetAttribute((const void*)gemm_kernel,
                            hipFuncAttributeMaxDynamicSharedMemorySize, 65536);
        attr_set = true;
    }

    hipLaunchKernelGGL(fusedA_kernel, dim3(1153), dim3(512), 0, stream,
                       x, mask, ln1, Wg2, Wb2, wcatT, iiA, jjA);
    hipLaunchKernelGGL(g1b1_kernel, dim3(128, 2), dim3(256), 0, stream,
                       x, mask, Wg1, Wb1, g1, b1, G1, B1);
    hipLaunchKernelGGL(innerstats_kernel, dim3(1024), dim3(256), 0, stream,
                       x, mask, lamtha, ln1, G1, B1, inner, mu2, inv2);
    hipLaunchKernelGGL(gemm_kernel, dim3(4112), dim3(256), 65536, stream,
                       inner, wcatT, g2, b2, ln1, G1, B1, iiA, jjA, mu2, inv2, out);
}